// Round 5
// baseline (292.654 us; speedup 1.0000x reference)
//
#include <hip/hip_runtime.h>
#include <stdint.h>

// ---------------------------------------------------------------------------
// GQA forward: y = OutProj( Attention( QKVProj(x) ) )
// B=2, S=2048, EMB=2048, NQH=16, HD=128, NKV=4, G=4. Non-causal softmax.
// R12: attn P kept fully in-register (T12-style): swapped-QK^T lane layout
//   P[q=l16][kv=cg*16+quad*4+r] is redistributed to the PV A-fragment layout
//   P[q=l16][kv=kc*32+quad*8+j] via 2x ds_bpermute + select per u32 slot
//   (conflict-free), replacing the Ps LDS staging (8x b64 write + 4x b128
//   read per wave/step, both 4-way bank-conflicted). Packing is the same
//   truncation as before -> bit-identical P and l. LDS 100.9 -> 64 KB.
// GEMMs (256^2 8-phase; 256x128 4-phase) and cvt unchanged from R11.
// ---------------------------------------------------------------------------

typedef short s8v __attribute__((ext_vector_type(8)));   // 8 bf16 = 16 B
typedef float f4  __attribute__((ext_vector_type(4)));
typedef unsigned short u16;
typedef unsigned int u32;

#define GLD_LDS(g, l) __builtin_amdgcn_global_load_lds(                     \
    (const __attribute__((address_space(1))) void*)(g),                     \
    (__attribute__((address_space(3))) void*)(l), 16, 0, 0)

__device__ __forceinline__ u16 f2bf(float f) {
    union { float f; uint32_t u; } v; v.f = f;
    uint32_t u = v.u;
    return (u16)((u + 0x7fffu + ((u >> 16) & 1u)) >> 16);   // RNE
}

__device__ __forceinline__ float fexp2(float x) {
#if __has_builtin(__builtin_amdgcn_exp2f)
    return __builtin_amdgcn_exp2f(x);
#else
    return exp2f(x);
#endif
}

// ----------------------- fused fp32 -> bf16 cast ----------------------------
__global__ void cvt_all(const float* __restrict__ x,  const float* __restrict__ wq,
                        const float* __restrict__ wk, const float* __restrict__ wv,
                        const float* __restrict__ wo_,
                        u16* __restrict__ xb, u16* __restrict__ wqkv,
                        u16* __restrict__ wob)
{
    int i = blockIdx.x * blockDim.x + threadIdx.x;
    const float4* s; ushort4* d; int so, dofs;
    if (i < 2097152)      { s = (const float4*)x;   d = (ushort4*)xb;   so = i;           dofs = so; }
    else if (i < 3145728) { s = (const float4*)wq;  d = (ushort4*)wqkv; so = i - 2097152; dofs = so; }
    else if (i < 3407872) { s = (const float4*)wk;  d = (ushort4*)wqkv; so = i - 3145728; dofs = so + 1048576; }
    else if (i < 3670016) { s = (const float4*)wv;  d = (ushort4*)wqkv; so = i - 3407872; dofs = so + 1310720; }
    else                  { s = (const float4*)wo_; d = (ushort4*)wob;  so = i - 3670016; dofs = so; }
    float4 v = s[so];
    ushort4 o;
    o.x = f2bf(v.x); o.y = f2bf(v.y); o.z = f2bf(v.z); o.w = f2bf(v.w);
    d[dofs] = o;
}

// ------------------- GEMM: C = A * B^T  (256x256, 8-phase) ------------------
template<int MODE>
__global__ __launch_bounds__(512, 2)
void gemm256(const u16* __restrict__ A, const u16* __restrict__ Bm,
             int M, int N, int K,
             u16* __restrict__ qkOut, u16* __restrict__ vtOut,
             float* __restrict__ fOut)
{
    __shared__ __attribute__((aligned(16))) u16 lds[2][2][2][8192];

    const int tid  = threadIdx.x;
    const int lane = tid & 63, quad = lane >> 4, l16 = lane & 15;
    const int wave = tid >> 6;
    const int wr = wave >> 2, wc = wave & 3;   // wave grid 2 x 4

    int bx, by;
    {
        const int nwgx = gridDim.x;
        const int nwg  = nwgx * gridDim.y;
        const int flat = blockIdx.y * nwgx + blockIdx.x;
        const int nflat = (flat & 7) * (nwg >> 3) + (flat >> 3);
        bx = nflat % nwgx; by = nflat / nwgx;
    }
    const int m0 = by * 256, n0 = bx * 256;
    const int NT = K >> 6;

    f4 acc[8][4] = {};

#define VMC6() asm volatile("s_waitcnt vmcnt(6)" ::: "memory")
#define VMC0() asm volatile("s_waitcnt vmcnt(0)" ::: "memory")
#define BAR()  __builtin_amdgcn_s_barrier()

#define STG(bf, op, h, t) if ((t) < NT) {                                   \
        const u16* gb = (op) ? Bm : A;                                      \
        const int rb = ((op) ? n0 : m0) + (h) * 128;                        \
        _Pragma("unroll")                                                   \
        for (int j = 0; j < 2; j++) {                                       \
            int s_ = j * 512 + tid;                                         \
            int r_ = s_ >> 3, cc = s_ & 7;                                  \
            GLD_LDS(gb + (size_t)(rb + r_) * K + (t) * 64                   \
                       + ((cc ^ (r_ & 7)) << 3),                            \
                    &lds[bf][op][h][(j * 512 + (tid & ~63)) * 8]);          \
        } }

#define RD_A(bf, qm, ar) {                                                  \
        _Pragma("unroll")                                                   \
        for (int f = 0; f < 4; f++) {                                       \
            int r_ = (qm) * 64 + f * 16 + l16;                              \
            _Pragma("unroll")                                               \
            for (int kc = 0; kc < 2; kc++)                                  \
                ar[f][kc] = *(const s8v*)(&lds[bf][0][wr]                   \
                    [r_ * 64 + (((kc * 4 + quad) ^ (r_ & 7)) << 3)]);       \
        } }

#define RD_B(bf, qn, br) {                                                  \
        _Pragma("unroll")                                                   \
        for (int f = 0; f < 2; f++) {                                       \
            int r_ = (wc & 1) * 64 + ((qn) * 2 + f) * 16 + l16;             \
            _Pragma("unroll")                                               \
            for (int kc = 0; kc < 2; kc++)                                  \
                br[f][kc] = *(const s8v*)(&lds[bf][1][wc >> 1]              \
                    [r_ * 64 + (((kc * 4 + quad) ^ (r_ & 7)) << 3)]);       \
        } }

#define MM(qm, qn, ar, br) {                                                \
        __builtin_amdgcn_s_setprio(1);                                      \
        _Pragma("unroll")                                                   \
        for (int f = 0; f < 4; f++)                                         \
            _Pragma("unroll")                                               \
            for (int g = 0; g < 2; g++) {                                   \
                acc[(qm)*4+f][(qn)*2+g] = __builtin_amdgcn_mfma_f32_16x16x32_bf16( \
                    ar[f][0], br[g][0], acc[(qm)*4+f][(qn)*2+g], 0, 0, 0);  \
                acc[(qm)*4+f][(qn)*2+g] = __builtin_amdgcn_mfma_f32_16x16x32_bf16( \
                    ar[f][1], br[g][1], acc[(qm)*4+f][(qn)*2+g], 0, 0, 0);  \
            }                                                               \
        __builtin_amdgcn_s_setprio(0); }

    STG(0,1,0,0); STG(0,1,1,0); STG(0,0,0,0); STG(0,0,1,0);
    STG(1,1,0,1); STG(1,1,1,1); STG(1,0,0,1);
    VMC6(); BAR();

    for (int T = 0; T < NT; T += 2) {
        const bool more = (T + 2 < NT);
        s8v a0[4][2], a1[4][2], b0[2][2], b1[2][2];
        RD_A(0,0,a0); RD_B(0,0,b0);
        STG(1,0,1,T+1);
        BAR(); MM(0,0,a0,b0); BAR();
        RD_B(0,1,b1);
        BAR(); MM(0,1,a0,b1); BAR();
        RD_A(0,1,a1);
        STG(0,1,0,T+2);
        BAR(); MM(1,0,a1,b0); BAR();
        STG(0,1,1,T+2); STG(0,0,0,T+2);
        BAR(); MM(1,1,a1,b1);
        if (more) { VMC6(); } else { VMC0(); }
        BAR();
        RD_A(1,0,a0); RD_B(1,0,b0);
        STG(0,0,1,T+2);
        BAR(); MM(0,0,a0,b0); BAR();
        RD_B(1,1,b1);
        BAR(); MM(0,1,a0,b1); BAR();
        RD_A(1,1,a1);
        STG(1,1,0,T+3);
        BAR(); MM(1,0,a1,b0); BAR();
        STG(1,1,1,T+3); STG(1,0,0,T+3);
        BAR(); MM(1,1,a1,b1);
        if (more) { VMC6(); } else { VMC0(); }
        BAR();
    }
#undef STG
#undef RD_A
#undef RD_B
#undef MM

    if (MODE == 0) {
        if (n0 < 2560) {
            const float qs = (n0 < 2048)
                ? (0.08838834764831845f * 1.4426950408889634f) : 1.0f;
            #pragma unroll
            for (int mi = 0; mi < 8; mi++) {
                int gm0 = m0 + wr * 128 + mi * 16 + quad * 4;
                #pragma unroll
                for (int ni = 0; ni < 4; ni++) {
                    int gn = n0 + wc * 64 + ni * 16 + l16;
                    #pragma unroll
                    for (int r = 0; r < 4; r++)
                        qkOut[(size_t)(gm0 + r) * 2560 + gn] = f2bf(acc[mi][ni][r] * qs);
                }
            }
        } else {
            #pragma unroll
            for (int mi = 0; mi < 8; mi++) {
                int gm0 = m0 + wr * 128 + mi * 16 + quad * 4;
                int bb = gm0 >> 11, s = gm0 & 2047;
                #pragma unroll
                for (int ni = 0; ni < 4; ni++) {
                    int gn = n0 + wc * 64 + ni * 16 + l16;
                    int dd = gn - 2560;
                    ushort4 pk;
                    pk.x = f2bf(acc[mi][ni][0]); pk.y = f2bf(acc[mi][ni][1]);
                    pk.z = f2bf(acc[mi][ni][2]); pk.w = f2bf(acc[mi][ni][3]);
                    *(ushort4*)(vtOut +
                        ((size_t)(bb * 4 + (dd >> 7)) * 128 + (dd & 127)) * 2048 + s) = pk;
                }
            }
        }
    } else {
        #pragma unroll
        for (int mi = 0; mi < 8; mi++) {
            int gm0 = m0 + wr * 128 + mi * 16 + quad * 4;
            #pragma unroll
            for (int ni = 0; ni < 4; ni++) {
                int gn = n0 + wc * 64 + ni * 16 + l16;
                #pragma unroll
                for (int r = 0; r < 4; r++)
                    fOut[(size_t)(gm0 + r) * N + gn] = acc[mi][ni][r];
            }
        }
    }
#undef VMC6
#undef VMC0
#undef BAR
}

// ---------------- GEMM: C = A * B^T  (256x128, 4-phase, fp32 out) -----------
__global__ __launch_bounds__(512, 1)
void gemm256x128(const u16* __restrict__ A, const u16* __restrict__ Bm,
                 int M, int N, int K, float* __restrict__ fOut)
{
    __shared__ __attribute__((aligned(16))) u16 lds[2][3][8192];

    const int tid  = threadIdx.x;
    const int lane = tid & 63, quad = lane >> 4, l16 = lane & 15;
    const int wave = tid >> 6;
    const int wr = wave >> 2, wc = wave & 3;

    int bx, by;
    {
        const int nwgx = gridDim.x;
        const int nwg  = nwgx * gridDim.y;
        const int flat = blockIdx.y * nwgx + blockIdx.x;
        const int nflat = (flat & 7) * (nwg >> 3) + (flat >> 3);
        bx = nflat % nwgx; by = nflat / nwgx;
    }
    const int m0 = by * 256, n0 = bx * 128;
    const int NT = K >> 6;

    f4 acc[8][2] = {};

#define VMC2() asm volatile("s_waitcnt vmcnt(2)" ::: "memory")
#define VMC0() asm volatile("s_waitcnt vmcnt(0)" ::: "memory")
#define BAR()  __builtin_amdgcn_s_barrier()

#define STG(bf, u, t) if ((t) < NT) {                                       \
        const u16* gb = ((u) == 2) ? Bm : A;                                \
        const int rb = ((u) == 2) ? n0 : (m0 + (u) * 128);                  \
        _Pragma("unroll")                                                   \
        for (int j = 0; j < 2; j++) {                                       \
            int s_ = j * 512 + tid;                                         \
            int r_ = s_ >> 3, cc = s_ & 7;                                  \
            GLD_LDS(gb + (size_t)(rb + r_) * K + (t) * 64                   \
                       + ((cc ^ (r_ & 7)) << 3),                            \
                    &lds[bf][u][(j * 512 + (tid & ~63)) * 8]);              \
        } }

#define RD_A(bf, qm, ar) {                                                  \
        _Pragma("unroll")                                                   \
        for (int f = 0; f < 4; f++) {                                       \
            int r_ = (qm) * 64 + f * 16 + l16;                              \
            _Pragma("unroll")                                               \
            for (int kc = 0; kc < 2; kc++)                                  \
                ar[f][kc] = *(const s8v*)(&lds[bf][wr]                      \
                    [r_ * 64 + (((kc * 4 + quad) ^ (r_ & 7)) << 3)]);       \
        } }

#define RD_B(bf, br) {                                                      \
        _Pragma("unroll")                                                   \
        for (int f = 0; f < 2; f++) {                                       \
            int r_ = wc * 32 + f * 16 + l16;                                \
            _Pragma("unroll")                                               \
            for (int kc = 0; kc < 2; kc++)                                  \
                br[f][kc] = *(const s8v*)(&lds[bf][2]                       \
                    [r_ * 64 + (((kc * 4 + quad) ^ (r_ & 7)) << 3)]);       \
        } }

#define MM(qm, ar, br) {                                                    \
        __builtin_amdgcn_s_setprio(1);                                      \
        _Pragma("unroll")                                                   \
        for (int f = 0; f < 4; f++)                                         \
            _Pragma("unroll")                                               \
            for (int g = 0; g < 2; g++) {                                   \
                acc[(qm)*4+f][g] = __builtin_amdgcn_mfma_f32_16x16x32_bf16( \
                    ar[f][0], br[g][0], acc[(qm)*4+f][g], 0, 0, 0);         \
                acc[(qm)*4+f][g] = __builtin_amdgcn_mfma_f32_16x16x32_bf16( \
                    ar[f][1], br[g][1], acc[(qm)*4+f][g], 0, 0, 0);         \
            }                                                               \
        __builtin_amdgcn_s_setprio(0); }

    STG(0,0,0); STG(0,1,0); STG(0,2,0);
    STG(1,2,1);
    VMC2(); BAR();

    for (int T = 0; T < NT; T += 2) {
        const bool more = (T + 2 < NT);
        s8v a0[4][2], a1[4][2], b[2][2];
        RD_A(0,0,a0); RD_B(0,b);
        STG(1,0,T+1); STG(1,1,T+1);
        BAR(); MM(0,a0,b); BAR();
        RD_A(0,1,a1);
        STG(0,2,T+2);
        BAR(); MM(1,a1,b);
        if (more) { VMC2(); } else { VMC0(); }
        BAR();
        RD_A(1,0,a0); RD_B(1,b);
        STG(0,0,T+2); STG(0,1,T+2);
        BAR(); MM(0,a0,b); BAR();
        RD_A(1,1,a1);
        STG(1,2,T+3);
        BAR(); MM(1,a1,b);
        if (more) { VMC2(); } else { VMC0(); }
        BAR();
    }
#undef STG
#undef RD_A
#undef RD_B
#undef MM
#undef VMC2
#undef VMC0
#undef BAR

    #pragma unroll
    for (int mi = 0; mi < 8; mi++) {
        int gm0 = m0 + wr * 128 + mi * 16 + quad * 4;
        #pragma unroll
        for (int ni = 0; ni < 2; ni++) {
            int gn = n0 + wc * 32 + ni * 16 + l16;
            #pragma unroll
            for (int r = 0; r < 4; r++)
                fOut[(size_t)(gm0 + r) * N + gn] = acc[mi][ni][r];
        }
    }
}

// ------------------------------- attention ----------------------------------
// grid = (B*NKV, S/64), 512 threads = 8 waves, wave = (head hh, m-half mh).
// R12: P fully in-register. After swapped QK^T, lane (l16,quad) holds
// P[q=l16][kv=cg*16+quad*4+r]. PV A-fragment needs P[q=l16][kv=kc*32+quad*8+j].
// Redistribution per u32 slot s (j=2s,2s+1): value = pk[cg=kc*2+b5][s&1] from
// src lane l16+32*b4+16*(s>>1)  (b4=quad&1, b5=quad>>1) -> 2x ds_bpermute +
// select. Packing = same truncation as R11's LDS path -> bit-identical P, l.
__global__ __launch_bounds__(512, 2)
void attn_kernel(const u16* __restrict__ qk, const u16* __restrict__ vt,
                 u16* __restrict__ ao)
{
    __shared__ __attribute__((aligned(16))) u16 Kb[2][64 * 128];  // 32 KB
    __shared__ __attribute__((aligned(16))) u16 Vb[2][128 * 64];  // 32 KB

    const int tid  = threadIdx.x;
    const int wave = tid >> 6, lane = tid & 63;
    const int quad = lane >> 4, l16 = lane & 15;
    const int bh = blockIdx.x;                 // 0..7 = b*4+h  (XCD = bh)
    const int b = bh >> 2, h = bh & 3;
    const int hh = wave >> 1, mh = wave & 1;   // head-in-group, m-half
    const int hq = h * 4 + hh;                 // global q-head
    const int qs0 = blockIdx.y * 64;
    const bool hi5 = (lane & 32) != 0;         // b5 = quad>>1

    // bpermute source addresses (bytes = 4*src_lane):
    // slot s<2: src = l16 + 32*(quad&1); slot s>=2: +16 lanes
    const int A0 = (l16 + ((quad & 1) << 5)) << 2;
    const int A1 = A0 + 64;

    s8v aq[2][4];
    #pragma unroll
    for (int mt = 0; mt < 2; mt++) {
        const u16* qrow = qk + (size_t)(b * 2048 + qs0 + (mh * 2 + mt) * 16 + l16) * 2560
                             + hq * 128 + quad * 8;
        #pragma unroll
        for (int c4 = 0; c4 < 4; c4++) aq[mt][c4] = *(const s8v*)(qrow + c4 * 32);
    }

    s8v ones;
    #pragma unroll
    for (int j = 0; j < 8; j++) ones[j] = (short)0x3F80;   // bf16 1.0

    f4 o[2][9] = {};          // 8 d-channels + [8] = row-sum l_i

    const u16* kbase = qk + (size_t)(b * 2048) * 2560 + 2048 + h * 128;
    const u16* vbase = vt + (size_t)bh * 128 * 2048;

    int bkb[4], bvb[2];
    #pragma unroll
    for (int c4 = 0; c4 < 4; c4++)
        bkb[c4] = l16 * 128 + (((c4 * 4 + quad) ^ (l16 & 7)) * 8);
    #pragma unroll
    for (int kc = 0; kc < 2; kc++)
        bvb[kc] = l16 * 64 + (((kc * 4 + quad) ^ (l16 & 7)) * 8);

#define STAGE(CUR, S) {                                                       \
        _Pragma("unroll")                                                     \
        for (int i = 0; i < 2; i++) {                                         \
            const int c = wave + i * 8;                                       \
            int kr = c * 4 + (lane >> 4);                                     \
            int ksw = (lane & 15) ^ (kr & 7);                                 \
            GLD_LDS(kbase + (size_t)((S) + kr) * 2560 + ksw * 8,              \
                    &Kb[CUR][c * 512]);                                       \
            int vd = c * 8 + (lane >> 3);                                     \
            int vsw = (lane & 7) ^ (vd & 7);                                  \
            GLD_LDS(vbase + (size_t)vd * 2048 + (S) + vsw * 8,                \
                    &Vb[CUR][c * 512]);                                       \
        } }

#define STEP(CUR, S) {                                                        \
        __syncthreads();  /* completes buf CUR staging (issued last iter) */  \
        if ((S) + 64 < 2048) STAGE((CUR) ^ 1, (S) + 64);                      \
        s8v bk[4][4];                                                         \
        _Pragma("unroll")                                                     \
        for (int c4 = 0; c4 < 4; c4++)                                        \
            _Pragma("unroll")                                                 \
            for (int cg = 0; cg < 4; cg++)                                    \
                bk[c4][cg] = *(const s8v*)(&Kb[CUR][bkb[c4] + cg * 2048]);    \
        s8v ap[2][2];                                                         \
        _Pragma("unroll")                                                     \
        for (int mt = 0; mt < 2; mt++) {                                      \
            f4 sc[4] = {};                                                    \
            _Pragma("unroll")                                                 \
            for (int c4 = 0; c4 < 4; c4++)                                    \
                _Pragma("unroll")                                             \
                for (int cg = 0; cg < 4; cg++)                                \
                    sc[cg] = __builtin_amdgcn_mfma_f32_16x16x32_bf16(         \
                        bk[c4][cg], aq[mt][c4], sc[cg], 0, 0, 0);             \
            u32 pk[4][2];                                                     \
            _Pragma("unroll")                                                 \
            for (int cg = 0; cg < 4; cg++) {                                  \
                u32 e0 = __float_as_uint(fexp2(sc[cg][0]));                   \
                u32 e1 = __float_as_uint(fexp2(sc[cg][1]));                   \
                u32 e2 = __float_as_uint(fexp2(sc[cg][2]));                   \
                u32 e3 = __float_as_uint(fexp2(sc[cg][3]));                   \
                pk[cg][0] = (e1 & 0xFFFF0000u) | (e0 >> 16);                  \
                pk[cg][1] = (e3 & 0xFFFF0000u) | (e2 >> 16);                  \
            }                                                                 \
            _Pragma("unroll")                                                 \
            for (int kc = 0; kc < 2; kc++) {                                  \
                union { u32 w[4]; s8v v; } uu;                                \
                _Pragma("unroll")                                             \
                for (int s = 0; s < 4; s++) {                                 \
                    int ad = (s & 2) ? A1 : A0;                               \
                    int lo = __builtin_amdgcn_ds_bpermute(ad, (int)pk[kc*2][s&1]);   \
                    int hi = __builtin_amdgcn_ds_bpermute(ad, (int)pk[kc*2+1][s&1]); \
                    uu.w[s] = hi5 ? (u32)hi : (u32)lo;                        \
                }                                                             \
                ap[mt][kc] = uu.v;                                            \
            }                                                                 \
        }                                                                     \
        _Pragma("unroll")                                                     \
        for (int ch = 0; ch < 8; ch++) {                                      \
            s8v bv0 = *(const s8v*)(&Vb[CUR][bvb[0] + ch * 1024]);            \
            s8v bv1 = *(const s8v*)(&Vb[CUR][bvb[1] + ch * 1024]);            \
            _Pragma("unroll")                                                 \
            for (int mt = 0; mt < 2; mt++) {                                  \
                o[mt][ch] = __builtin_amdgcn_mfma_f32_16x16x32_bf16(          \
                    ap[mt][0], bv0, o[mt][ch], 0, 0, 0);                      \
                o[mt][ch] = __builtin_amdgcn_mfma_f32_16x16x32_bf16(          \
                    ap[mt][1], bv1, o[mt][ch], 0, 0, 0);                      \
            }                                                                 \
        }                                                                     \
        _Pragma("unroll")                                                     \
        for (int mt = 0; mt < 2; mt++) {                                      \
            o[mt][8] = __builtin_amdgcn_mfma_f32_16x16x32_bf16(               \
                ap[mt][0], ones, o[mt][8], 0, 0, 0);                          \
            o[mt][8] = __builtin_amdgcn_mfma_f32_16x16x32_bf16(               \
                ap[mt][1], ones, o[mt][8], 0, 0, 0);                          \
        } }

    STAGE(0, 0);
    for (int s0 = 0; s0 < 2048; s0 += 128) {
        STEP(0, s0);
        STEP(1, s0 + 64);
    }
#undef STEP
#undef STAGE

    #pragma unroll
    for (int mt = 0; mt < 2; mt++)
        #pragma unroll
        for (int r = 0; r < 4; r++) {
            float inv = 1.f / o[mt][8][r];
            int gm = b * 2048 + qs0 + (mh * 2 + mt) * 16 + quad * 4 + r;
            #pragma unroll
            for (int ch = 0; ch < 8; ch++)
                ao[(size_t)gm * 2048 + hq * 128 + ch * 16 + l16] =
                    f2bf(o[mt][ch][r] * inv);
        }
}

// ------------------------------- launcher -----------------------------------
extern "C" void kernel_launch(void* const* d_in, const int* in_sizes, int n_in,
                              void* d_out, int out_size, void* d_ws, size_t ws_size,
                              hipStream_t stream)
{
    const float* x  = (const float*)d_in[0];
    const float* Wq = (const float*)d_in[3];
    const float* Wk = (const float*)d_in[4];
    const float* Wv = (const float*)d_in[5];
    const float* Wo = (const float*)d_in[6];

    char* ws = (char*)d_ws;
    u16* xb   = (u16*)(ws);                 // 4096x2048
    u16* wqkv = (u16*)(ws + 16777216);      // 3072x2048
    u16* wo   = (u16*)(ws + 29360128);      // 2048x2048
    u16* qkb  = (u16*)(ws + 37748736);      // 4096x2560
    u16* vtb  = (u16*)(ws + 58720256);      // 2x4x128x2048
    u16* ao   = (u16*)(ws + 62914560);      // 4096x2048
    if (ws_size < 79691776u) return;

    cvt_all<<<18432, 256, 0, stream>>>(x, Wq, Wk, Wv, Wo, xb, wqkv, wo);

    gemm256<0><<<dim3(12, 16), 512, 0, stream>>>(xb, wqkv, 4096, 3072, 2048,
                                                 qkb, vtb, nullptr);
    attn_kernel<<<dim3(8, 32), 512, 0, stream>>>(qkb, vtb, ao);
    gemm256x128<<<dim3(16, 16), 512, 0, stream>>>(ao, wo, 4096, 2048, 2048,
                                                  (float*)d_out);
}

// Round 6
// 278.907 us; speedup vs baseline: 1.0493x; 1.0493x over previous
//
#include <hip/hip_runtime.h>
#include <stdint.h>

// ---------------------------------------------------------------------------
// GQA forward: y = OutProj( Attention( QKVProj(x) ) )
// B=2, S=2048, EMB=2048, NQH=16, HD=128, NKV=4, G=4. Non-causal softmax.
// R13:
//  - attn: REVERT to R11 (Ps LDS staging, b64 P-writes; 76.6 us measured).
//    R12's ds_bpermute path regressed (85.1 us): bpermute is an LDS-pipe op
//    (32 b32 crossbar ops/step = same LDS cycles) + longer serial chain.
//  - gemm256: __launch_bounds__(512,2) -> (512,1). The (512,2) form capped
//    the allocator at 256 VGPR with a ~220-250 live set (acc 128 + frags 64+
//    + staging addrs) -> likely scratch spills in the K-loop, matching the
//    observed ~2.5x GEMM underperformance. LDS (128KB) limits to 1 block/CU
//    regardless, so the cap buys nothing. Zero-risk single-variable test.
// gemm256x128 (out-proj) unchanged from R11.
// ---------------------------------------------------------------------------

typedef short s8v __attribute__((ext_vector_type(8)));   // 8 bf16 = 16 B
typedef float f4  __attribute__((ext_vector_type(4)));
typedef unsigned short u16;

#define GLD_LDS(g, l) __builtin_amdgcn_global_load_lds(                     \
    (const __attribute__((address_space(1))) void*)(g),                     \
    (__attribute__((address_space(3))) void*)(l), 16, 0, 0)

__device__ __forceinline__ u16 f2bf(float f) {
    union { float f; uint32_t u; } v; v.f = f;
    uint32_t u = v.u;
    return (u16)((u + 0x7fffu + ((u >> 16) & 1u)) >> 16);   // RNE
}

__device__ __forceinline__ float fexp2(float x) {
#if __has_builtin(__builtin_amdgcn_exp2f)
    return __builtin_amdgcn_exp2f(x);
#else
    return exp2f(x);
#endif
}

// ----------------------- fused fp32 -> bf16 cast ----------------------------
__global__ void cvt_all(const float* __restrict__ x,  const float* __restrict__ wq,
                        const float* __restrict__ wk, const float* __restrict__ wv,
                        const float* __restrict__ wo_,
                        u16* __restrict__ xb, u16* __restrict__ wqkv,
                        u16* __restrict__ wob)
{
    int i = blockIdx.x * blockDim.x + threadIdx.x;
    const float4* s; ushort4* d; int so, dofs;
    if (i < 2097152)      { s = (const float4*)x;   d = (ushort4*)xb;   so = i;           dofs = so; }
    else if (i < 3145728) { s = (const float4*)wq;  d = (ushort4*)wqkv; so = i - 2097152; dofs = so; }
    else if (i < 3407872) { s = (const float4*)wk;  d = (ushort4*)wqkv; so = i - 3145728; dofs = so + 1048576; }
    else if (i < 3670016) { s = (const float4*)wv;  d = (ushort4*)wqkv; so = i - 3407872; dofs = so + 1310720; }
    else                  { s = (const float4*)wo_; d = (ushort4*)wob;  so = i - 3670016; dofs = so; }
    float4 v = s[so];
    ushort4 o;
    o.x = f2bf(v.x); o.y = f2bf(v.y); o.z = f2bf(v.z); o.w = f2bf(v.w);
    d[dofs] = o;
}

// ------------------- GEMM: C = A * B^T  (256x256, 8-phase) ------------------
// MODE 0: QKV epilogue -> qkOut [M,2560]; V -> vtOut transposed.
template<int MODE>
__global__ __launch_bounds__(512, 1)   // R13: lift VGPR cap (LDS limits 1/CU)
void gemm256(const u16* __restrict__ A, const u16* __restrict__ Bm,
             int M, int N, int K,
             u16* __restrict__ qkOut, u16* __restrict__ vtOut,
             float* __restrict__ fOut)
{
    __shared__ __attribute__((aligned(16))) u16 lds[2][2][2][8192];

    const int tid  = threadIdx.x;
    const int lane = tid & 63, quad = lane >> 4, l16 = lane & 15;
    const int wave = tid >> 6;
    const int wr = wave >> 2, wc = wave & 3;   // wave grid 2 x 4

    int bx, by;
    {
        const int nwgx = gridDim.x;
        const int nwg  = nwgx * gridDim.y;
        const int flat = blockIdx.y * nwgx + blockIdx.x;
        const int nflat = (flat & 7) * (nwg >> 3) + (flat >> 3);
        bx = nflat % nwgx; by = nflat / nwgx;
    }
    const int m0 = by * 256, n0 = bx * 256;
    const int NT = K >> 6;

    f4 acc[8][4] = {};

#define VMC6() asm volatile("s_waitcnt vmcnt(6)" ::: "memory")
#define VMC0() asm volatile("s_waitcnt vmcnt(0)" ::: "memory")
#define BAR()  __builtin_amdgcn_s_barrier()

#define STG(bf, op, h, t) if ((t) < NT) {                                   \
        const u16* gb = (op) ? Bm : A;                                      \
        const int rb = ((op) ? n0 : m0) + (h) * 128;                        \
        _Pragma("unroll")                                                   \
        for (int j = 0; j < 2; j++) {                                       \
            int s_ = j * 512 + tid;                                         \
            int r_ = s_ >> 3, cc = s_ & 7;                                  \
            GLD_LDS(gb + (size_t)(rb + r_) * K + (t) * 64                   \
                       + ((cc ^ (r_ & 7)) << 3),                            \
                    &lds[bf][op][h][(j * 512 + (tid & ~63)) * 8]);          \
        } }

#define RD_A(bf, qm, ar) {                                                  \
        _Pragma("unroll")                                                   \
        for (int f = 0; f < 4; f++) {                                       \
            int r_ = (qm) * 64 + f * 16 + l16;                              \
            _Pragma("unroll")                                               \
            for (int kc = 0; kc < 2; kc++)                                  \
                ar[f][kc] = *(const s8v*)(&lds[bf][0][wr]                   \
                    [r_ * 64 + (((kc * 4 + quad) ^ (r_ & 7)) << 3)]);       \
        } }

#define RD_B(bf, qn, br) {                                                  \
        _Pragma("unroll")                                                   \
        for (int f = 0; f < 2; f++) {                                       \
            int r_ = (wc & 1) * 64 + ((qn) * 2 + f) * 16 + l16;             \
            _Pragma("unroll")                                               \
            for (int kc = 0; kc < 2; kc++)                                  \
                br[f][kc] = *(const s8v*)(&lds[bf][1][wc >> 1]              \
                    [r_ * 64 + (((kc * 4 + quad) ^ (r_ & 7)) << 3)]);       \
        } }

#define MM(qm, qn, ar, br) {                                                \
        __builtin_amdgcn_s_setprio(1);                                      \
        _Pragma("unroll")                                                   \
        for (int f = 0; f < 4; f++)                                         \
            _Pragma("unroll")                                               \
            for (int g = 0; g < 2; g++) {                                   \
                acc[(qm)*4+f][(qn)*2+g] = __builtin_amdgcn_mfma_f32_16x16x32_bf16( \
                    ar[f][0], br[g][0], acc[(qm)*4+f][(qn)*2+g], 0, 0, 0);  \
                acc[(qm)*4+f][(qn)*2+g] = __builtin_amdgcn_mfma_f32_16x16x32_bf16( \
                    ar[f][1], br[g][1], acc[(qm)*4+f][(qn)*2+g], 0, 0, 0);  \
            }                                                               \
        __builtin_amdgcn_s_setprio(0); }

    STG(0,1,0,0); STG(0,1,1,0); STG(0,0,0,0); STG(0,0,1,0);
    STG(1,1,0,1); STG(1,1,1,1); STG(1,0,0,1);
    VMC6(); BAR();

    for (int T = 0; T < NT; T += 2) {
        const bool more = (T + 2 < NT);
        s8v a0[4][2], a1[4][2], b0[2][2], b1[2][2];
        RD_A(0,0,a0); RD_B(0,0,b0);
        STG(1,0,1,T+1);
        BAR(); MM(0,0,a0,b0); BAR();
        RD_B(0,1,b1);
        BAR(); MM(0,1,a0,b1); BAR();
        RD_A(0,1,a1);
        STG(0,1,0,T+2);
        BAR(); MM(1,0,a1,b0); BAR();
        STG(0,1,1,T+2); STG(0,0,0,T+2);
        BAR(); MM(1,1,a1,b1);
        if (more) { VMC6(); } else { VMC0(); }
        BAR();
        RD_A(1,0,a0); RD_B(1,0,b0);
        STG(0,0,1,T+2);
        BAR(); MM(0,0,a0,b0); BAR();
        RD_B(1,1,b1);
        BAR(); MM(0,1,a0,b1); BAR();
        RD_A(1,1,a1);
        STG(1,1,0,T+3);
        BAR(); MM(1,0,a1,b0); BAR();
        STG(1,1,1,T+3); STG(1,0,0,T+3);
        BAR(); MM(1,1,a1,b1);
        if (more) { VMC6(); } else { VMC0(); }
        BAR();
    }
#undef STG
#undef RD_A
#undef RD_B
#undef MM

    if (MODE == 0) {
        if (n0 < 2560) {
            const float qs = (n0 < 2048)
                ? (0.08838834764831845f * 1.4426950408889634f) : 1.0f;
            #pragma unroll
            for (int mi = 0; mi < 8; mi++) {
                int gm0 = m0 + wr * 128 + mi * 16 + quad * 4;
                #pragma unroll
                for (int ni = 0; ni < 4; ni++) {
                    int gn = n0 + wc * 64 + ni * 16 + l16;
                    #pragma unroll
                    for (int r = 0; r < 4; r++)
                        qkOut[(size_t)(gm0 + r) * 2560 + gn] = f2bf(acc[mi][ni][r] * qs);
                }
            }
        } else {
            #pragma unroll
            for (int mi = 0; mi < 8; mi++) {
                int gm0 = m0 + wr * 128 + mi * 16 + quad * 4;
                int bb = gm0 >> 11, s = gm0 & 2047;
                #pragma unroll
                for (int ni = 0; ni < 4; ni++) {
                    int gn = n0 + wc * 64 + ni * 16 + l16;
                    int dd = gn - 2560;
                    ushort4 pk;
                    pk.x = f2bf(acc[mi][ni][0]); pk.y = f2bf(acc[mi][ni][1]);
                    pk.z = f2bf(acc[mi][ni][2]); pk.w = f2bf(acc[mi][ni][3]);
                    *(ushort4*)(vtOut +
                        ((size_t)(bb * 4 + (dd >> 7)) * 128 + (dd & 127)) * 2048 + s) = pk;
                }
            }
        }
    } else {
        #pragma unroll
        for (int mi = 0; mi < 8; mi++) {
            int gm0 = m0 + wr * 128 + mi * 16 + quad * 4;
            #pragma unroll
            for (int ni = 0; ni < 4; ni++) {
                int gn = n0 + wc * 64 + ni * 16 + l16;
                #pragma unroll
                for (int r = 0; r < 4; r++)
                    fOut[(size_t)(gm0 + r) * N + gn] = acc[mi][ni][r];
            }
        }
    }
#undef VMC6
#undef VMC0
#undef BAR
}

// ---------------- GEMM: C = A * B^T  (256x128, 4-phase, fp32 out) -----------
__global__ __launch_bounds__(512, 1)
void gemm256x128(const u16* __restrict__ A, const u16* __restrict__ Bm,
                 int M, int N, int K, float* __restrict__ fOut)
{
    __shared__ __attribute__((aligned(16))) u16 lds[2][3][8192];

    const int tid  = threadIdx.x;
    const int lane = tid & 63, quad = lane >> 4, l16 = lane & 15;
    const int wave = tid >> 6;
    const int wr = wave >> 2, wc = wave & 3;

    int bx, by;
    {
        const int nwgx = gridDim.x;
        const int nwg  = nwgx * gridDim.y;
        const int flat = blockIdx.y * nwgx + blockIdx.x;
        const int nflat = (flat & 7) * (nwg >> 3) + (flat >> 3);
        bx = nflat % nwgx; by = nflat / nwgx;
    }
    const int m0 = by * 256, n0 = bx * 128;
    const int NT = K >> 6;

    f4 acc[8][2] = {};

#define VMC2() asm volatile("s_waitcnt vmcnt(2)" ::: "memory")
#define VMC0() asm volatile("s_waitcnt vmcnt(0)" ::: "memory")
#define BAR()  __builtin_amdgcn_s_barrier()

#define STG(bf, u, t) if ((t) < NT) {                                       \
        const u16* gb = ((u) == 2) ? Bm : A;                                \
        const int rb = ((u) == 2) ? n0 : (m0 + (u) * 128);                  \
        _Pragma("unroll")                                                   \
        for (int j = 0; j < 2; j++) {                                       \
            int s_ = j * 512 + tid;                                         \
            int r_ = s_ >> 3, cc = s_ & 7;                                  \
            GLD_LDS(gb + (size_t)(rb + r_) * K + (t) * 64                   \
                       + ((cc ^ (r_ & 7)) << 3),                            \
                    &lds[bf][u][(j * 512 + (tid & ~63)) * 8]);              \
        } }

#define RD_A(bf, qm, ar) {                                                  \
        _Pragma("unroll")                                                   \
        for (int f = 0; f < 4; f++) {                                       \
            int r_ = (qm) * 64 + f * 16 + l16;                              \
            _Pragma("unroll")                                               \
            for (int kc = 0; kc < 2; kc++)                                  \
                ar[f][kc] = *(const s8v*)(&lds[bf][wr]                      \
                    [r_ * 64 + (((kc * 4 + quad) ^ (r_ & 7)) << 3)]);       \
        } }

#define RD_B(bf, br) {                                                      \
        _Pragma("unroll")                                                   \
        for (int f = 0; f < 2; f++) {                                       \
            int r_ = wc * 32 + f * 16 + l16;                                \
            _Pragma("unroll")                                               \
            for (int kc = 0; kc < 2; kc++)                                  \
                br[f][kc] = *(const s8v*)(&lds[bf][2]                       \
                    [r_ * 64 + (((kc * 4 + quad) ^ (r_ & 7)) << 3)]);       \
        } }

#define MM(qm, ar, br) {                                                    \
        __builtin_amdgcn_s_setprio(1);                                      \
        _Pragma("unroll")                                                   \
        for (int f = 0; f < 4; f++)                                         \
            _Pragma("unroll")                                               \
            for (int g = 0; g < 2; g++) {                                   \
                acc[(qm)*4+f][g] = __builtin_amdgcn_mfma_f32_16x16x32_bf16( \
                    ar[f][0], br[g][0], acc[(qm)*4+f][g], 0, 0, 0);         \
                acc[(qm)*4+f][g] = __builtin_amdgcn_mfma_f32_16x16x32_bf16( \
                    ar[f][1], br[g][1], acc[(qm)*4+f][g], 0, 0, 0);         \
            }                                                               \
        __builtin_amdgcn_s_setprio(0); }

    STG(0,0,0); STG(0,1,0); STG(0,2,0);
    STG(1,2,1);
    VMC2(); BAR();

    for (int T = 0; T < NT; T += 2) {
        const bool more = (T + 2 < NT);
        s8v a0[4][2], a1[4][2], b[2][2];
        RD_A(0,0,a0); RD_B(0,b);
        STG(1,0,T+1); STG(1,1,T+1);
        BAR(); MM(0,a0,b); BAR();
        RD_A(0,1,a1);
        STG(0,2,T+2);
        BAR(); MM(1,a1,b);
        if (more) { VMC2(); } else { VMC0(); }
        BAR();
        RD_A(1,0,a0); RD_B(1,b);
        STG(0,0,T+2); STG(0,1,T+2);
        BAR(); MM(0,a0,b); BAR();
        RD_A(1,1,a1);
        STG(1,2,T+3);
        BAR(); MM(1,a1,b);
        if (more) { VMC2(); } else { VMC0(); }
        BAR();
    }
#undef STG
#undef RD_A
#undef RD_B
#undef MM
#undef VMC2
#undef VMC0
#undef BAR

    #pragma unroll
    for (int mi = 0; mi < 8; mi++) {
        int gm0 = m0 + wr * 128 + mi * 16 + quad * 4;
        #pragma unroll
        for (int ni = 0; ni < 2; ni++) {
            int gn = n0 + wc * 32 + ni * 16 + l16;
            #pragma unroll
            for (int r = 0; r < 4; r++)
                fOut[(size_t)(gm0 + r) * N + gn] = acc[mi][ni][r];
        }
    }
}

// ------------------------------- attention ----------------------------------
// grid = (B*NKV, S/64), 512 threads = 8 waves, wave = (head hh, m-half mh).
// R11 version (reverted): swapped QK^T, P staged via 8x ds_write_b64 + b128
// reads; no max-tracking (P = exp2(S) unnormalized, l via ones-MFMA).
__global__ __launch_bounds__(512, 2)
void attn_kernel(const u16* __restrict__ qk, const u16* __restrict__ vt,
                 u16* __restrict__ ao)
{
    __shared__ __attribute__((aligned(16))) u16 Kb[2][64 * 128];  // 32 KB
    __shared__ __attribute__((aligned(16))) u16 Vb[2][128 * 64];  // 32 KB
    __shared__ __attribute__((aligned(16))) u16 Ps[8][32 * 72];   // 36 KB

    const int tid  = threadIdx.x;
    const int wave = tid >> 6, lane = tid & 63;
    const int quad = lane >> 4, l16 = lane & 15;
    const int bh = blockIdx.x;                 // 0..7 = b*4+h  (XCD = bh)
    const int b = bh >> 2, h = bh & 3;
    const int hh = wave >> 1, mh = wave & 1;   // head-in-group, m-half
    const int hq = h * 4 + hh;                 // global q-head
    const int qs0 = blockIdx.y * 64;

    s8v aq[2][4];
    #pragma unroll
    for (int mt = 0; mt < 2; mt++) {
        const u16* qrow = qk + (size_t)(b * 2048 + qs0 + (mh * 2 + mt) * 16 + l16) * 2560
                             + hq * 128 + quad * 8;
        #pragma unroll
        for (int c4 = 0; c4 < 4; c4++) aq[mt][c4] = *(const s8v*)(qrow + c4 * 32);
    }

    s8v ones;
    #pragma unroll
    for (int j = 0; j < 8; j++) ones[j] = (short)0x3F80;   // bf16 1.0

    f4 o[2][9] = {};          // 8 d-channels + [8] = row-sum l_i

    const u16* kbase = qk + (size_t)(b * 2048) * 2560 + 2048 + h * 128;
    const u16* vbase = vt + (size_t)bh * 128 * 2048;
    u16* Pw = &Ps[wave][0];

    int bkb[4], bvb[2];
    #pragma unroll
    for (int c4 = 0; c4 < 4; c4++)
        bkb[c4] = l16 * 128 + (((c4 * 4 + quad) ^ (l16 & 7)) * 8);
    #pragma unroll
    for (int kc = 0; kc < 2; kc++)
        bvb[kc] = l16 * 64 + (((kc * 4 + quad) ^ (l16 & 7)) * 8);
    const int apb = l16 * 72 + quad * 8;        // + mt*1152 + kc*32
    const int psw = l16 * 72 + quad * 4;        // + mt*1152 + cg*16 (b64 write)

#define STAGE(CUR, S) {                                                       \
        _Pragma("unroll")                                                     \
        for (int i = 0; i < 2; i++) {                                         \
            const int c = wave + i * 8;                                       \
            int kr = c * 4 + (lane >> 4);                                     \
            int ksw = (lane & 15) ^ (kr & 7);                                 \
            GLD_LDS(kbase + (size_t)((S) + kr) * 2560 + ksw * 8,              \
                    &Kb[CUR][c * 512]);                                       \
            int vd = c * 8 + (lane >> 3);                                     \
            int vsw = (lane & 7) ^ (vd & 7);                                  \
            GLD_LDS(vbase + (size_t)vd * 2048 + (S) + vsw * 8,                \
                    &Vb[CUR][c * 512]);                                       \
        } }

#define STEP(CUR, S) {                                                        \
        __syncthreads();  /* completes buf CUR staging (issued last iter) */  \
        if ((S) + 64 < 2048) STAGE((CUR) ^ 1, (S) + 64);                      \
        s8v bk[4][4];                                                         \
        _Pragma("unroll")                                                     \
        for (int c4 = 0; c4 < 4; c4++)                                        \
            _Pragma("unroll")                                                 \
            for (int cg = 0; cg < 4; cg++)                                    \
                bk[c4][cg] = *(const s8v*)(&Kb[CUR][bkb[c4] + cg * 2048]);    \
        _Pragma("unroll")                                                     \
        for (int mt = 0; mt < 2; mt++) {                                      \
            f4 sc[4] = {};                                                    \
            _Pragma("unroll")                                                 \
            for (int c4 = 0; c4 < 4; c4++)                                    \
                _Pragma("unroll")                                             \
                for (int cg = 0; cg < 4; cg++)                                \
                    sc[cg] = __builtin_amdgcn_mfma_f32_16x16x32_bf16(         \
                        bk[c4][cg], aq[mt][c4], sc[cg], 0, 0, 0);             \
            /* P = exp2(S): lane holds (q=l16, kv=quad*4+r) -> b64 write */   \
            _Pragma("unroll")                                                 \
            for (int cg = 0; cg < 4; cg++) {                                  \
                ushort4 pk;                                                   \
                pk.x = (u16)(__float_as_uint(fexp2(sc[cg][0])) >> 16);        \
                pk.y = (u16)(__float_as_uint(fexp2(sc[cg][1])) >> 16);        \
                pk.z = (u16)(__float_as_uint(fexp2(sc[cg][2])) >> 16);        \
                pk.w = (u16)(__float_as_uint(fexp2(sc[cg][3])) >> 16);        \
                *(ushort4*)(Pw + psw + mt * 1152 + cg * 16) = pk;             \
            }                                                                 \
        }                                                                     \
        s8v ap[2][2];                                                         \
        _Pragma("unroll")                                                     \
        for (int mt = 0; mt < 2; mt++)                                        \
            _Pragma("unroll")                                                 \
            for (int kc = 0; kc < 2; kc++)                                    \
                ap[mt][kc] = *(const s8v*)(Pw + apb + mt * 1152 + kc * 32);   \
        _Pragma("unroll")                                                     \
        for (int ch = 0; ch < 8; ch++) {                                      \
            s8v bv0 = *(const s8v*)(&Vb[CUR][bvb[0] + ch * 1024]);            \
            s8v bv1 = *(const s8v*)(&Vb[CUR][bvb[1] + ch * 1024]);            \
            _Pragma("unroll")                                                 \
            for (int mt = 0; mt < 2; mt++) {                                  \
                o[mt][ch] = __builtin_amdgcn_mfma_f32_16x16x32_bf16(          \
                    ap[mt][0], bv0, o[mt][ch], 0, 0, 0);                      \
                o[mt][ch] = __builtin_amdgcn_mfma_f32_16x16x32_bf16(          \
                    ap[mt][1], bv1, o[mt][ch], 0, 0, 0);                      \
            }                                                                 \
        }                                                                     \
        _Pragma("unroll")                                                     \
        for (int mt = 0; mt < 2; mt++) {                                      \
            o[mt][8] = __builtin_amdgcn_mfma_f32_16x16x32_bf16(               \
                ap[mt][0], ones, o[mt][8], 0, 0, 0);                          \
            o[mt][8] = __builtin_amdgcn_mfma_f32_16x16x32_bf16(               \
                ap[mt][1], ones, o[mt][8], 0, 0, 0);                          \
        } }

    STAGE(0, 0);
    for (int s0 = 0; s0 < 2048; s0 += 128) {
        STEP(0, s0);
        STEP(1, s0 + 64);
    }
#undef STEP
#undef STAGE

    #pragma unroll
    for (int mt = 0; mt < 2; mt++)
        #pragma unroll
        for (int r = 0; r < 4; r++) {
            float inv = 1.f / o[mt][8][r];
            int gm = b * 2048 + qs0 + (mh * 2 + mt) * 16 + quad * 4 + r;
            #pragma unroll
            for (int ch = 0; ch < 8; ch++)
                ao[(size_t)gm * 2048 + hq * 128 + ch * 16 + l16] =
                    f2bf(o[mt][ch][r] * inv);
        }
}

// ------------------------------- launcher -----------------------------------
extern "C" void kernel_launch(void* const* d_in, const int* in_sizes, int n_in,
                              void* d_out, int out_size, void* d_ws, size_t ws_size,
                              hipStream_t stream)
{
    const float* x  = (const float*)d_in[0];
    const float* Wq = (const float*)d_in[3];
    const float* Wk = (const float*)d_in[4];
    const float* Wv = (const float*)d_in[5];
    const float* Wo = (const float*)d_in[6];

    char* ws = (char*)d_ws;
    u16* xb   = (u16*)(ws);                 // 4096x2048
    u16* wqkv = (u16*)(ws + 16777216);      // 3072x2048
    u16* wo   = (u16*)(ws + 29360128);      // 2048x2048
    u16* qkb  = (u16*)(ws + 37748736);      // 4096x2560
    u16* vtb  = (u16*)(ws + 58720256);      // 2x4x128x2048
    u16* ao   = (u16*)(ws + 62914560);      // 4096x2048
    if (ws_size < 79691776u) return;

    cvt_all<<<18432, 256, 0, stream>>>(x, Wq, Wk, Wv, Wo, xb, wqkv, wo);

    gemm256<0><<<dim3(12, 16), 512, 0, stream>>>(xb, wqkv, 4096, 3072, 2048,
                                                 qkb, vtb, nullptr);
    attn_kernel<<<dim3(8, 32), 512, 0, stream>>>(qkb, vtb, ao);
    gemm256x128<<<dim3(16, 16), 512, 0, stream>>>(ao, wo, 4096, 2048, 2048,
                                                  (float*)d_out);
}